// Round 1
// baseline (695.893 us; speedup 1.0000x reference)
//
#include <hip/hip_runtime.h>

#define N_NODES 4096
#define N_EDGES 65536
#define M_CH 16
#define MID 32
#define BN_EPS 1e-5f

// ---- workspace layout (float offsets) ----
#define WS_RSUM    0
#define WS_RSUMSQ  1
#define WS_SUM2    16     // [4][32] layer2 pre-act sums
#define WS_SUMSQ2  144    // [4][32]
#define WS_ALPHA1  272    // [4][32]
#define WS_BETA1   400    // [4][32]
#define WS_A2      528    // [4][32]
#define WS_S2      656    // [4][32]
#define WS_DEG     1024   // int[N]
#define WS_W2T     8192   // [4][32][32]  (p,c,k)  transposed layer2 weights
#define WS_W3T00   12288  // [256][32]    col-major layer3 weights
#define WS_W3T01   20480
#define WS_W3T10   28672
#define WS_W3T11   36864  // [768][32]
// total 61440 floats = 240 KB

// ---------- K0: transpose weights into ws (column-major, 32-deep contiguous) ----------
__global__ void k_prep(const float* __restrict__ rw2, const float* __restrict__ w300,
                       const float* __restrict__ w301, const float* __restrict__ w310,
                       const float* __restrict__ w311, float* __restrict__ wsf) {
    int t = blockIdx.x * 256 + threadIdx.x;   // grid covers 24576
    if (t < 4096) {
        int p = t >> 10, rem = t & 1023, c = rem >> 5, k = rem & 31;
        wsf[WS_W2T + t] = rw2[(p << 10) + (k << 5) + c];      // [p][c][k] <- [p][k][c]
    }
    if (t < 8192) {
        int col = t >> 5, k = t & 31;
        wsf[WS_W3T00 + t] = w300[(k << 8) + col];
        wsf[WS_W3T01 + t] = w301[(k << 8) + col];
        wsf[WS_W3T10 + t] = w310[(k << 8) + col];
    }
    if (t < 24576) {
        int col = t >> 5, k = t & 31;
        wsf[WS_W3T11 + t] = w311[k * 768 + col];
    }
}

// ---------- K1: stats of r (mean/var) + degree counts ----------
__global__ void k_stats1(const float* __restrict__ r, const int* __restrict__ edst,
                         float* __restrict__ wsf) {
    int t = blockIdx.x * 256 + threadIdx.x;   // grid = E threads
    float v = r[t];
    atomicAdd(((int*)wsf) + WS_DEG + edst[t], 1);
    float s = v, ss = v * v;
#pragma unroll
    for (int mk = 32; mk >= 1; mk >>= 1) {
        s  += __shfl_xor(s,  mk, 64);
        ss += __shfl_xor(ss, mk, 64);
    }
    __shared__ float ls[4], lss[4];
    int lane = threadIdx.x & 63, wv = threadIdx.x >> 6;
    if (lane == 0) { ls[wv] = s; lss[wv] = ss; }
    __syncthreads();
    if (threadIdx.x == 0) {
        atomicAdd(wsf + WS_RSUM,   ls[0] + ls[1] + ls[2] + ls[3]);
        atomicAdd(wsf + WS_RSUMSQ, lss[0] + lss[1] + lss[2] + lss[3]);
    }
}

// ---------- K2: stats of layer-2 pre-activations (needs K1) ----------
__global__ void __launch_bounds__(256) k_stats2(const float* __restrict__ r,
        const float* __restrict__ rw1, const float* __restrict__ rg1,
        const float* __restrict__ rbe1, const float* __restrict__ rb2,
        float* __restrict__ wsf) {
    int lane = threadIdx.x & 63;
    int wv = threadIdx.x >> 6;
    int phalf = __builtin_amdgcn_readfirstlane(wv & 1);     // wave-uniform pair half
    int e = blockIdx.x * 128 + ((wv >> 1) << 6) + lane;     // grid 512 blocks
    float rv = r[e];
    float mu_r  = wsf[WS_RSUM] * (1.f / N_EDGES);
    float var_r = wsf[WS_RSUMSQ] * (1.f / N_EDGES) - mu_r * mu_r;
    __shared__ float sacc[128], sacc2[128];
    if (threadIdx.x < 128) { sacc[threadIdx.x] = 0.f; sacc2[threadIdx.x] = 0.f; }
    __syncthreads();
    for (int pp = 0; pp < 2; ++pp) {
        int p = phalf * 2 + pp;
        float y1[MID];
#pragma unroll
        for (int k = 0; k < MID; ++k) {
            float w1 = rw1[p * 32 + k];
            float al = w1 * rg1[p * 32 + k] * rsqrtf(w1 * w1 * var_r + BN_EPS);
            y1[k] = fmaxf(0.f, al * (rv - mu_r) + rbe1[p * 32 + k]);
        }
        for (int c = 0; c < MID; ++c) {
            float x = rb2[p * 32 + c];
#pragma unroll
            for (int k = 0; k < MID; ++k) x += y1[k] * wsf[WS_W2T + p * 1024 + c * 32 + k];
            float xs = x, xx = x * x;
#pragma unroll
            for (int mk = 32; mk >= 1; mk >>= 1) {
                xs += __shfl_xor(xs, mk, 64);
                xx += __shfl_xor(xx, mk, 64);
            }
            if (lane == 0) { atomicAdd(&sacc[p * 32 + c], xs); atomicAdd(&sacc2[p * 32 + c], xx); }
        }
    }
    __syncthreads();
    if (threadIdx.x < 128) {
        atomicAdd(wsf + WS_SUM2   + threadIdx.x, sacc[threadIdx.x]);
        atomicAdd(wsf + WS_SUMSQ2 + threadIdx.x, sacc2[threadIdx.x]);
    }
}

// ---------- K3: finalize BN affine params ----------
__global__ void k_finalize(const float* __restrict__ rw1, const float* __restrict__ rg1,
                           const float* __restrict__ rbe1, const float* __restrict__ rg2,
                           const float* __restrict__ rbe2, float* __restrict__ wsf) {
    int t = threadIdx.x;   // 128
    float mu_r  = wsf[WS_RSUM] * (1.f / N_EDGES);
    float var_r = wsf[WS_RSUMSQ] * (1.f / N_EDGES) - mu_r * mu_r;
    float w1 = rw1[t];
    float al = w1 * rg1[t] * rsqrtf(w1 * w1 * var_r + BN_EPS);
    wsf[WS_ALPHA1 + t] = al;
    wsf[WS_BETA1  + t] = rbe1[t] - al * mu_r;
    float mu2 = wsf[WS_SUM2 + t] * (1.f / N_EDGES);
    float v2  = wsf[WS_SUMSQ2 + t] * (1.f / N_EDGES) - mu2 * mu2;
    float a2  = rg2[t] * rsqrtf(v2 + BN_EPS);
    wsf[WS_A2 + t] = a2;
    wsf[WS_S2 + t] = rbe2[t] - mu2 * a2;
}

// y1 -> y2 for pair p (all indices static => registers; weight/param reads wave-uniform => s_load)
__device__ __forceinline__ void compute_y2(int p, float rv, const float* __restrict__ wsf,
                                           const float* __restrict__ rb2, float* y2) {
    float y1[MID];
#pragma unroll
    for (int k = 0; k < MID; ++k)
        y1[k] = fmaxf(0.f, wsf[WS_ALPHA1 + p * 32 + k] * rv + wsf[WS_BETA1 + p * 32 + k]);
#pragma unroll
    for (int c = 0; c < MID; ++c) {
        float x = rb2[p * 32 + c];
#pragma unroll
        for (int k = 0; k < MID; ++k) x += y1[k] * wsf[WS_W2T + p * 1024 + c * 32 + k];
        y2[c] = fmaxf(0.f, wsf[WS_A2 + p * 32 + c] * x + wsf[WS_S2 + p * 32 + c]);
    }
}

// ---------- K4: main per-edge kernel. 1 lane = 1 edge, m-split=2 across waves ----------
__global__ void __launch_bounds__(256, 2) k_main(const float* __restrict__ r,
        const float* __restrict__ h0, const float* __restrict__ h1,
        const float* __restrict__ b00, const float* __restrict__ b01,
        const float* __restrict__ b10, const float* __restrict__ b11,
        const float* __restrict__ rb2,
        const float* __restrict__ bw300, const float* __restrict__ bw301,
        const float* __restrict__ bw310, const float* __restrict__ bw311,
        const int* __restrict__ esrc, const int* __restrict__ edst,
        const float* __restrict__ wsf, float* __restrict__ out) {
    int lane = threadIdx.x & 63;
    int wv = threadIdx.x >> 6;
    int m0 = __builtin_amdgcn_readfirstlane((wv & 1) << 3);  // wave-uniform m-offset: 0 or 8
    int e = blockIdx.x * 128 + ((wv >> 1) << 6) + lane;      // grid 512 blocks
    int s = esrc[e], d = edst[e];
    float rv = r[e];

    float acc0[8];
#pragma unroll
    for (int mm = 0; mm < 8; ++mm) acc0[mm] = 0.f;

    // ---- pair (0,0): msg0 += basis00 * (R00 @ h0s) ----
    {
        float y2[MID]; compute_y2(0, rv, wsf, rb2, y2);
        const float* W = wsf + WS_W3T00;
        float d00[8];
#pragma unroll
        for (int mm = 0; mm < 8; ++mm) d00[mm] = 0.f;
#pragma unroll 2
        for (int i = 0; i < 16; ++i) {
            float hv = h0[s * 16 + i];
#pragma unroll
            for (int mm = 0; mm < 8; ++mm) {
                int col = (m0 + mm) * 16 + i;
                float racc = bw300[col];
#pragma unroll
                for (int k = 0; k < MID; ++k) racc += y2[k] * W[col * 32 + k];
                d00[mm] += racc * hv;
            }
        }
        float bs = b00[e];
#pragma unroll
        for (int mm = 0; mm < 8; ++mm) acc0[mm] = bs * d00[mm];
    }

    // ---- pair (1,0): msg0 += R10 @ (basis10 . h1s) ----
    {
        float y2[MID]; compute_y2(2, rv, wsf, rb2, y2);
        const float* W = wsf + WS_W3T10;
        float bq0 = b10[e * 3 + 0], bq1 = b10[e * 3 + 1], bq2 = b10[e * 3 + 2];
#pragma unroll 2
        for (int i = 0; i < 16; ++i) {
            float gi = bq0 * h1[s * 48 + i * 3 + 0] + bq1 * h1[s * 48 + i * 3 + 1]
                     + bq2 * h1[s * 48 + i * 3 + 2];
#pragma unroll
            for (int mm = 0; mm < 8; ++mm) {
                int col = (m0 + mm) * 16 + i;
                float racc = bw310[col];
#pragma unroll
                for (int k = 0; k < MID; ++k) racc += y2[k] * W[col * 32 + k];
                acc0[mm] += racc * gi;
            }
        }
    }
#pragma unroll
    for (int mm = 0; mm < 8; ++mm) atomicAdd(out + d * 16 + m0 + mm, acc0[mm]);

    // ---- pair (0,1): d01[m] = R01 @ h0s (combined with basis01 at flush) ----
    float d01[8];
    {
        float y2[MID]; compute_y2(1, rv, wsf, rb2, y2);
        const float* W = wsf + WS_W3T01;
#pragma unroll
        for (int mm = 0; mm < 8; ++mm) d01[mm] = 0.f;
#pragma unroll 2
        for (int i = 0; i < 16; ++i) {
            float hv = h0[s * 16 + i];
#pragma unroll
            for (int mm = 0; mm < 8; ++mm) {
                int col = (m0 + mm) * 16 + i;
                float racc = bw301[col];
#pragma unroll
                for (int k = 0; k < MID; ++k) racc += y2[k] * W[col * 32 + k];
                d01[mm] += racc * hv;
            }
        }
    }

    // ---- pair (1,1): msg1[m,o] += sum_{i,f} R11[m,i,f] * T[i,o,f] ----
    float msg1[8][3];
#pragma unroll
    for (int mm = 0; mm < 8; ++mm)
#pragma unroll
        for (int o = 0; o < 3; ++o) msg1[mm][o] = 0.f;
    {
        float y2[MID]; compute_y2(3, rv, wsf, rb2, y2);
        const float* W = wsf + WS_W3T11;
        float bas[27];
#pragma unroll
        for (int j = 0; j < 27; ++j) bas[j] = b11[e * 27 + j];
#pragma unroll 1
        for (int i = 0; i < 16; ++i) {
            float hq0 = h1[s * 48 + i * 3 + 0], hq1 = h1[s * 48 + i * 3 + 1],
                  hq2 = h1[s * 48 + i * 3 + 2];
            float T[3][3];
#pragma unroll
            for (int o = 0; o < 3; ++o)
#pragma unroll
                for (int f = 0; f < 3; ++f)
                    T[o][f] = hq0 * bas[o * 9 + 0 + f] + hq1 * bas[o * 9 + 3 + f]
                            + hq2 * bas[o * 9 + 6 + f];
#pragma unroll
            for (int mm = 0; mm < 8; ++mm) {
#pragma unroll
                for (int f = 0; f < 3; ++f) {
                    int col = ((m0 + mm) * 16 + i) * 3 + f;
                    float racc = bw311[col];
#pragma unroll
                    for (int k = 0; k < MID; ++k) racc += y2[k] * W[col * 32 + k];
#pragma unroll
                    for (int o = 0; o < 3; ++o) msg1[mm][o] += racc * T[o][f];
                }
            }
        }
    }
    float bo0 = b01[e * 3 + 0], bo1 = b01[e * 3 + 1], bo2 = b01[e * 3 + 2];
    float* out1 = out + 65536;
#pragma unroll
    for (int mm = 0; mm < 8; ++mm) {
        atomicAdd(out1 + d * 48 + (m0 + mm) * 3 + 0, msg1[mm][0] + bo0 * d01[mm]);
        atomicAdd(out1 + d * 48 + (m0 + mm) * 3 + 1, msg1[mm][1] + bo1 * d01[mm]);
        atomicAdd(out1 + d * 48 + (m0 + mm) * 3 + 2, msg1[mm][2] + bo2 * d01[mm]);
    }
}

// ---------- K5: divide by cnt, add per-node self-interaction ----------
__global__ void k_final(const float* __restrict__ h0, const float* __restrict__ h1,
                        const float* __restrict__ Wself0, const float* __restrict__ Wself1,
                        const float* __restrict__ wsf, float* __restrict__ out) {
    int t = blockIdx.x * 256 + threadIdx.x;   // 262144 total
    const int* deg = ((const int*)wsf) + WS_DEG;
    if (t < 65536) {
        int n = t >> 4, m = t & 15;
        int dg = deg[n];
        float self = 0.f;
#pragma unroll
        for (int i = 0; i < 16; ++i) self += Wself0[m * 16 + i] * h0[n * 16 + i];
        float c = (float)(dg > 0 ? dg : 1);
        out[t] = out[t] / c + (dg > 0 ? self : 0.f);
    } else {
        int t2 = t - 65536;
        int n = t2 / 48, rem = t2 % 48, m = rem / 3, o = rem % 3;
        int dg = deg[n];
        float self = 0.f;
#pragma unroll
        for (int i = 0; i < 16; ++i) self += Wself1[m * 16 + i] * h1[n * 48 + i * 3 + o];
        float c = (float)(dg > 0 ? dg : 1);
        out[t] = out[t] / c + (dg > 0 ? self : 0.f);
    }
}

extern "C" void kernel_launch(void* const* d_in, const int* in_sizes, int n_in,
                              void* d_out, int out_size, void* d_ws, size_t ws_size,
                              hipStream_t stream) {
    const float* h0   = (const float*)d_in[0];
    const float* h1   = (const float*)d_in[1];
    const float* r    = (const float*)d_in[2];
    const float* b00  = (const float*)d_in[3];
    const float* b01  = (const float*)d_in[4];
    const float* b10  = (const float*)d_in[5];
    const float* b11  = (const float*)d_in[6];
    const float* rw1  = (const float*)d_in[7];
    // d_in[8] = rb1: cancels inside BatchNorm (shifts x1 and mu1 equally)
    const float* rg1  = (const float*)d_in[9];
    const float* rbe1 = (const float*)d_in[10];
    const float* rw2  = (const float*)d_in[11];
    const float* rb2  = (const float*)d_in[12];
    const float* rg2  = (const float*)d_in[13];
    const float* rbe2 = (const float*)d_in[14];
    const float* w300 = (const float*)d_in[15];
    const float* bw300= (const float*)d_in[16];
    const float* w301 = (const float*)d_in[17];
    const float* bw301= (const float*)d_in[18];
    const float* w310 = (const float*)d_in[19];
    const float* bw310= (const float*)d_in[20];
    const float* w311 = (const float*)d_in[21];
    const float* bw311= (const float*)d_in[22];
    const float* Wself0 = (const float*)d_in[23];
    const float* Wself1 = (const float*)d_in[24];
    const int* esrc = (const int*)d_in[25];
    const int* edst = (const int*)d_in[26];
    float* out = (float*)d_out;
    float* wsf = (float*)d_ws;

    hipMemsetAsync(d_out, 0, (size_t)out_size * sizeof(float), stream);
    hipMemsetAsync(d_ws, 0, 8192 * sizeof(float), stream);  // stats + deg region

    k_prep<<<96, 256, 0, stream>>>(rw2, w300, w301, w310, w311, wsf);
    k_stats1<<<256, 256, 0, stream>>>(r, edst, wsf);
    k_stats2<<<512, 256, 0, stream>>>(r, rw1, rg1, rbe1, rb2, wsf);
    k_finalize<<<1, 128, 0, stream>>>(rw1, rg1, rbe1, rg2, rbe2, wsf);
    k_main<<<512, 256, 0, stream>>>(r, h0, h1, b00, b01, b10, b11, rb2,
                                    bw300, bw301, bw310, bw311, esrc, edst, wsf, out);
    k_final<<<1024, 256, 0, stream>>>(h0, h1, Wself0, Wself1, wsf, out);
}

// Round 2
// 479.036 us; speedup vs baseline: 1.4527x; 1.4527x over previous
//
#include <hip/hip_runtime.h>

#define N_NODES 4096
#define N_EDGES 65536
#define MID 32
#define BN_EPS 1e-5f

// ---- workspace layout ----
// float offsets:
#define WS_RSUM    0
#define WS_RSUMSQ  1
#define WS_SUM2    16     // [4][32] layer2 pre-act sums
#define WS_SUMSQ2  144
#define WS_ALPHA1  272
#define WS_BETA1   400
#define WS_A2      528
#define WS_S2      656
#define WS_DEG     1024   // int[4096]
#define WS_W2T     8192   // [4][32][32] fp32, (p,c,k) transposed layer2 weights
// byte offsets:
#define WSB_W3ABC  49152  // 768 cols x 32 bf16, [col][k]: 0-255 p00 (m*16+i), 256-511 p01, 512-767 p10
#define WSB_W311   98304  // 768 cols x 32 bf16, [col'][k], col' = f*256 + m*16 + i
#define WSB_B3     147456 // 1536 fp32: 0-255 p00, 256-511 p01, 512-767 p10, 768-1535 p11 (f*256+m*16+i)
// end: 153600 bytes

typedef short bf16x8 __attribute__((ext_vector_type(8)));
typedef float f32x4  __attribute__((ext_vector_type(4)));

__device__ __forceinline__ unsigned short f2bf(float x) {
    unsigned u = __float_as_uint(x);
    u += 0x7fffu + ((u >> 16) & 1u);   // round-to-nearest-even
    return (unsigned short)(u >> 16);
}

// ---------- K0: build weight images (W2T fp32, W3 bf16 col-major, b3 images) ----------
__global__ void k_prep(const float* __restrict__ rw2, const float* __restrict__ w300,
                       const float* __restrict__ w301, const float* __restrict__ w310,
                       const float* __restrict__ w311,
                       const float* __restrict__ bw300, const float* __restrict__ bw301,
                       const float* __restrict__ bw310, const float* __restrict__ bw311,
                       float* __restrict__ wsf) {
    int t = blockIdx.x * 256 + threadIdx.x;   // grid 128x256 = 32768
    char* wsb = (char*)wsf;
    if (t < 4096) {   // W2T [p][c][k] <- rw2 [p][k][c]
        int p = t >> 10, rem = t & 1023, c = rem >> 5, k = rem & 31;
        wsf[WS_W2T + t] = rw2[(p << 10) + (k << 5) + c];
    }
    if (t < 24576) {  // 768 cols x 32 k
        int col = t >> 5, k = t & 31;
        // ABC image
        float v;
        if (col < 256)      v = w300[(k << 8) + col];
        else if (col < 512) v = w301[(k << 8) + (col - 256)];
        else                v = w310[(k << 8) + (col - 512)];
        ((unsigned short*)(wsb + WSB_W3ABC))[t] = f2bf(v);
        // pair11 image, permuted col' = f*256 + m*16 + i  <- src col (m*16+i)*3+f
        int f = col >> 8, rem = col & 255;
        ((unsigned short*)(wsb + WSB_W311))[t] = f2bf(w311[k * 768 + rem * 3 + f]);
    }
    if (t < 1536) {   // b3 image
        float v;
        if (t < 256)      v = bw300[t];
        else if (t < 512) v = bw301[t - 256];
        else if (t < 768) v = bw310[t - 512];
        else { int idx = t - 768; int f = idx >> 8, rem = idx & 255; v = bw311[rem * 3 + f]; }
        ((float*)(wsb + WSB_B3))[t] = v;
    }
}

// ---------- K1: stats of r + degree counts ----------
__global__ void k_stats1(const float* __restrict__ r, const int* __restrict__ edst,
                         float* __restrict__ wsf) {
    int t = blockIdx.x * 256 + threadIdx.x;   // grid = E threads
    float v = r[t];
    atomicAdd(((int*)wsf) + WS_DEG + edst[t], 1);
    float s = v, ss = v * v;
#pragma unroll
    for (int mk = 32; mk >= 1; mk >>= 1) {
        s  += __shfl_xor(s,  mk, 64);
        ss += __shfl_xor(ss, mk, 64);
    }
    __shared__ float ls[4], lss[4];
    int lane = threadIdx.x & 63, wv = threadIdx.x >> 6;
    if (lane == 0) { ls[wv] = s; lss[wv] = ss; }
    __syncthreads();
    if (threadIdx.x == 0) {
        atomicAdd(wsf + WS_RSUM,   ls[0] + ls[1] + ls[2] + ls[3]);
        atomicAdd(wsf + WS_RSUMSQ, lss[0] + lss[1] + lss[2] + lss[3]);
    }
}

// ---------- K2: stats of layer-2 pre-activations ----------
__global__ void __launch_bounds__(256) k_stats2(const float* __restrict__ r,
        const float* __restrict__ rw1, const float* __restrict__ rg1,
        const float* __restrict__ rbe1, const float* __restrict__ rb2,
        float* __restrict__ wsf) {
    int lane = threadIdx.x & 63;
    int wv = threadIdx.x >> 6;
    int phalf = __builtin_amdgcn_readfirstlane(wv & 1);
    int e = blockIdx.x * 128 + ((wv >> 1) << 6) + lane;     // grid 512 blocks
    float rv = r[e];
    float mu_r  = wsf[WS_RSUM] * (1.f / N_EDGES);
    float var_r = wsf[WS_RSUMSQ] * (1.f / N_EDGES) - mu_r * mu_r;
    __shared__ float sacc[128], sacc2[128];
    if (threadIdx.x < 128) { sacc[threadIdx.x] = 0.f; sacc2[threadIdx.x] = 0.f; }
    __syncthreads();
    for (int pp = 0; pp < 2; ++pp) {
        int p = __builtin_amdgcn_readfirstlane(phalf * 2 + pp);
        float y1[MID];
#pragma unroll
        for (int k = 0; k < MID; ++k) {
            float w1 = rw1[p * 32 + k];
            float al = w1 * rg1[p * 32 + k] * rsqrtf(w1 * w1 * var_r + BN_EPS);
            y1[k] = fmaxf(0.f, al * (rv - mu_r) + rbe1[p * 32 + k]);
        }
        for (int c = 0; c < MID; ++c) {
            float x = rb2[p * 32 + c];
#pragma unroll
            for (int k = 0; k < MID; ++k) x += y1[k] * wsf[WS_W2T + p * 1024 + c * 32 + k];
            float xs = x, xx = x * x;
#pragma unroll
            for (int mk = 32; mk >= 1; mk >>= 1) {
                xs += __shfl_xor(xs, mk, 64);
                xx += __shfl_xor(xx, mk, 64);
            }
            if (lane == 0) { atomicAdd(&sacc[p * 32 + c], xs); atomicAdd(&sacc2[p * 32 + c], xx); }
        }
    }
    __syncthreads();
    if (threadIdx.x < 128) {
        atomicAdd(wsf + WS_SUM2   + threadIdx.x, sacc[threadIdx.x]);
        atomicAdd(wsf + WS_SUMSQ2 + threadIdx.x, sacc2[threadIdx.x]);
    }
}

// ---------- K3: finalize BN affine params ----------
__global__ void k_finalize(const float* __restrict__ rw1, const float* __restrict__ rg1,
                           const float* __restrict__ rbe1, const float* __restrict__ rg2,
                           const float* __restrict__ rbe2, float* __restrict__ wsf) {
    int t = threadIdx.x;   // 128
    float mu_r  = wsf[WS_RSUM] * (1.f / N_EDGES);
    float var_r = wsf[WS_RSUMSQ] * (1.f / N_EDGES) - mu_r * mu_r;
    float w1 = rw1[t];
    float al = w1 * rg1[t] * rsqrtf(w1 * w1 * var_r + BN_EPS);
    wsf[WS_ALPHA1 + t] = al;
    wsf[WS_BETA1  + t] = rbe1[t] - al * mu_r;
    float mu2 = wsf[WS_SUM2 + t] * (1.f / N_EDGES);
    float v2  = wsf[WS_SUMSQ2 + t] * (1.f / N_EDGES) - mu2 * mu2;
    float a2  = rg2[t] * rsqrtf(v2 + BN_EPS);
    wsf[WS_A2 + t] = a2;
    wsf[WS_S2 + t] = rbe2[t] - mu2 * a2;
}

// ---------- K4: MFMA main kernel ----------
// block = 512 threads (8 waves), 256 edges/block, grid 256 blocks.
// LDS: w3l  = 768 cols x 32 bf16 [col][k]                   : 49152 B
//      y2b  = [p:4][chunk q:4][e:256][16 B]                 : 65536 B   total 114688 B
__global__ void __launch_bounds__(512, 1) k_main(const float* __restrict__ r,
        const float* __restrict__ h0, const float* __restrict__ h1,
        const float* __restrict__ b00, const float* __restrict__ b01,
        const float* __restrict__ b10, const float* __restrict__ b11,
        const float* __restrict__ rb2,
        const int* __restrict__ esrc, const int* __restrict__ edst,
        const float* __restrict__ wsf, float* __restrict__ out) {
    extern __shared__ char smem[];
    short* w3l = (short*)smem;
    char*  y2b = smem + 49152;
    const char* wsb = (const char*)wsf;
    int t = threadIdx.x;
    // stage W3 (pairs 00/01/10) bf16 image: 49152 B = 3072 float4
    {
        const float4* src = (const float4*)(wsb + WSB_W3ABC);
        float4* dst = (float4*)w3l;
#pragma unroll
        for (int i = 0; i < 6; ++i) dst[i * 512 + t] = src[i * 512 + t];
    }
    int wv = t >> 6, lane = t & 63;
    int eb = blockIdx.x << 8;

    // ---- phase 1: y2 (fp32) -> bf16 chunks in LDS. lane owns edge, pair wave-uniform ----
    {
        int el = ((wv & 3) << 6) | lane;                 // block-local edge 0..255
        int ph = __builtin_amdgcn_readfirstlane(wv >> 2);
        float rv = r[eb + el];
#pragma unroll
        for (int pp = 0; pp < 2; ++pp) {
            int p = __builtin_amdgcn_readfirstlane(ph * 2 + pp);
            float y1[MID];
#pragma unroll
            for (int k = 0; k < MID; ++k)
                y1[k] = fmaxf(0.f, wsf[WS_ALPHA1 + p * 32 + k] * rv + wsf[WS_BETA1 + p * 32 + k]);
            unsigned short y2h[MID];
#pragma unroll
            for (int c = 0; c < MID; ++c) {
                float x = rb2[p * 32 + c];
#pragma unroll
                for (int k = 0; k < MID; ++k) x += y1[k] * wsf[WS_W2T + p * 1024 + c * 32 + k];
                float y2v = fmaxf(0.f, wsf[WS_A2 + p * 32 + c] * x + wsf[WS_S2 + p * 32 + c]);
                y2h[c] = f2bf(y2v);
            }
#pragma unroll
            for (int q = 0; q < 4; ++q) {
                int4 pk;
                pk.x = (int)y2h[q * 8 + 0] | ((int)y2h[q * 8 + 1] << 16);
                pk.y = (int)y2h[q * 8 + 2] | ((int)y2h[q * 8 + 3] << 16);
                pk.z = (int)y2h[q * 8 + 4] | ((int)y2h[q * 8 + 5] << 16);
                pk.w = (int)y2h[q * 8 + 6] | ((int)y2h[q * 8 + 7] << 16);
                *(int4*)(y2b + p * 16384 + q * 4096 + el * 16) = pk;
            }
        }
    }
    __syncthreads();

    // ---- phase 2: per-16-edge-group MFMA + apply ----
    int quad = lane >> 4, lq = lane & 15;
    const float* b3img = (const float*)(wsb + WSB_B3);
    const short* w3g11 = (const short*)(wsb + WSB_W311);
    float* out1 = out + 65536;

#pragma unroll 1
    for (int g2 = 0; g2 < 2; ++g2) {
        int g = wv * 2 + g2;                  // 0..15
        int el = g * 16 + lq;
        int e = eb + el;
        int s = esrc[e], d = edst[e];
        // B fragments (y2 of this edge, k-chunk = quad)
        bf16x8 bfr[4];
#pragma unroll
        for (int p = 0; p < 4; ++p)
            bfr[p] = *(const bf16x8*)(y2b + p * 16384 + quad * 4096 + el * 16);
        float h0q[4];
#pragma unroll
        for (int rr = 0; rr < 4; ++rr) h0q[rr] = h0[s * 16 + quad * 4 + rr];
        float h1v[4][3];
#pragma unroll
        for (int rr = 0; rr < 4; ++rr)
#pragma unroll
            for (int qq = 0; qq < 3; ++qq) h1v[rr][qq] = h1[s * 48 + (quad * 4 + rr) * 3 + qq];

        float acc0[4] = {0.f, 0.f, 0.f, 0.f};
        float d01q[4] = {0.f, 0.f, 0.f, 0.f};
        float b00v = b00[e];

        // ---- pair (0,0) -> acc0 ----
#pragma unroll
        for (int m = 0; m < 16; ++m) {
            bf16x8 af = *(const bf16x8*)(w3l + (m * 16 + lq) * 32 + quad * 8);
            f32x4 dd = __builtin_amdgcn_mfma_f32_16x16x32_bf16(af, bfr[0], (f32x4){0.f,0.f,0.f,0.f}, 0, 0, 0);
            float4 b3v = *(const float4*)(b3img + m * 16 + quad * 4);
            float partial = (dd[0] + b3v.x) * h0q[0] + (dd[1] + b3v.y) * h0q[1]
                          + (dd[2] + b3v.z) * h0q[2] + (dd[3] + b3v.w) * h0q[3];
            partial += __shfl_xor(partial, 16);
            partial += __shfl_xor(partial, 32);
            float v = b00v * partial;
            acc0[m & 3] += (quad == (m >> 2)) ? v : 0.f;
        }
        // ---- pair (0,1) -> d01q ----
#pragma unroll
        for (int m = 0; m < 16; ++m) {
            bf16x8 af = *(const bf16x8*)(w3l + (256 + m * 16 + lq) * 32 + quad * 8);
            f32x4 dd = __builtin_amdgcn_mfma_f32_16x16x32_bf16(af, bfr[1], (f32x4){0.f,0.f,0.f,0.f}, 0, 0, 0);
            float4 b3v = *(const float4*)(b3img + 256 + m * 16 + quad * 4);
            float partial = (dd[0] + b3v.x) * h0q[0] + (dd[1] + b3v.y) * h0q[1]
                          + (dd[2] + b3v.z) * h0q[2] + (dd[3] + b3v.w) * h0q[3];
            partial += __shfl_xor(partial, 16);
            partial += __shfl_xor(partial, 32);
            d01q[m & 3] += (quad == (m >> 2)) ? partial : 0.f;
        }
        // ---- pair (1,0) -> acc0 ----
        {
            float bq0 = b10[e * 3 + 0], bq1 = b10[e * 3 + 1], bq2 = b10[e * 3 + 2];
            float gq[4];
#pragma unroll
            for (int rr = 0; rr < 4; ++rr)
                gq[rr] = bq0 * h1v[rr][0] + bq1 * h1v[rr][1] + bq2 * h1v[rr][2];
#pragma unroll
            for (int m = 0; m < 16; ++m) {
                bf16x8 af = *(const bf16x8*)(w3l + (512 + m * 16 + lq) * 32 + quad * 8);
                f32x4 dd = __builtin_amdgcn_mfma_f32_16x16x32_bf16(af, bfr[2], (f32x4){0.f,0.f,0.f,0.f}, 0, 0, 0);
                float4 b3v = *(const float4*)(b3img + 512 + m * 16 + quad * 4);
                float partial = (dd[0] + b3v.x) * gq[0] + (dd[1] + b3v.y) * gq[1]
                              + (dd[2] + b3v.z) * gq[2] + (dd[3] + b3v.w) * gq[3];
                partial += __shfl_xor(partial, 16);
                partial += __shfl_xor(partial, 32);
                acc0[m & 3] += (quad == (m >> 2)) ? partial : 0.f;
            }
        }
#pragma unroll
        for (int rr = 0; rr < 4; ++rr)
            atomicAdd(out + d * 16 + quad * 4 + rr, acc0[rr]);

        // ---- pair (1,1) -> msg1 (+ b01*d01) ----
        float T[4][3][3];   // [rr][o][f]
        {
            float basv[3][3][3];   // [o][qq][f]
#pragma unroll
            for (int o = 0; o < 3; ++o)
#pragma unroll
                for (int qq = 0; qq < 3; ++qq)
#pragma unroll
                    for (int f = 0; f < 3; ++f)
                        basv[o][qq][f] = b11[e * 27 + o * 9 + qq * 3 + f];
#pragma unroll
            for (int rr = 0; rr < 4; ++rr)
#pragma unroll
                for (int o = 0; o < 3; ++o)
#pragma unroll
                    for (int f = 0; f < 3; ++f)
                        T[rr][o][f] = h1v[rr][0] * basv[o][0][f] + h1v[rr][1] * basv[o][1][f]
                                    + h1v[rr][2] * basv[o][2][f];
        }
        float m1[4][3];
#pragma unroll
        for (int rr = 0; rr < 4; ++rr)
#pragma unroll
            for (int o = 0; o < 3; ++o) m1[rr][o] = 0.f;
#pragma unroll 1
        for (int f = 0; f < 3; ++f) {
#pragma unroll
            for (int m = 0; m < 16; ++m) {
                int colb = f * 256 + m * 16 + lq;
                bf16x8 af = *(const bf16x8*)(w3g11 + colb * 32 + quad * 8);  // global, L2-hot
                f32x4 dd = __builtin_amdgcn_mfma_f32_16x16x32_bf16(af, bfr[3], (f32x4){0.f,0.f,0.f,0.f}, 0, 0, 0);
                float4 b3v = *(const float4*)(b3img + 768 + f * 256 + m * 16 + quad * 4);
                float dr0 = dd[0] + b3v.x, dr1 = dd[1] + b3v.y, dr2 = dd[2] + b3v.z, dr3 = dd[3] + b3v.w;
#pragma unroll
                for (int o = 0; o < 3; ++o) {
                    float po = dr0 * T[0][o][f] + dr1 * T[1][o][f] + dr2 * T[2][o][f] + dr3 * T[3][o][f];
                    po += __shfl_xor(po, 16);
                    po += __shfl_xor(po, 32);
                    m1[m & 3][o] += (quad == (m >> 2)) ? po : 0.f;
                }
            }
        }
        float b01v0 = b01[e * 3 + 0], b01v1 = b01[e * 3 + 1], b01v2 = b01[e * 3 + 2];
#pragma unroll
        for (int rr = 0; rr < 4; ++rr) {
            m1[rr][0] += b01v0 * d01q[rr];
            m1[rr][1] += b01v1 * d01q[rr];
            m1[rr][2] += b01v2 * d01q[rr];
        }
#pragma unroll
        for (int rr = 0; rr < 4; ++rr)
#pragma unroll
            for (int o = 0; o < 3; ++o)
                atomicAdd(out1 + d * 48 + (quad * 4 + rr) * 3 + o, m1[rr][o]);
    }
}

// ---------- K5: divide by cnt, add self-interaction ----------
__global__ void k_final(const float* __restrict__ h0, const float* __restrict__ h1,
                        const float* __restrict__ Wself0, const float* __restrict__ Wself1,
                        const float* __restrict__ wsf, float* __restrict__ out) {
    int t = blockIdx.x * 256 + threadIdx.x;   // 262144 total
    const int* deg = ((const int*)wsf) + WS_DEG;
    if (t < 65536) {
        int n = t >> 4, m = t & 15;
        int dg = deg[n];
        float self = 0.f;
#pragma unroll
        for (int i = 0; i < 16; ++i) self += Wself0[m * 16 + i] * h0[n * 16 + i];
        float c = (float)(dg > 0 ? dg : 1);
        out[t] = out[t] / c + (dg > 0 ? self : 0.f);
    } else {
        int t2 = t - 65536;
        int n = t2 / 48, rem = t2 % 48, m = rem / 3, o = rem % 3;
        int dg = deg[n];
        float self = 0.f;
#pragma unroll
        for (int i = 0; i < 16; ++i) self += Wself1[m * 16 + i] * h1[n * 48 + i * 3 + o];
        float c = (float)(dg > 0 ? dg : 1);
        out[t] = out[t] / c + (dg > 0 ? self : 0.f);
    }
}

extern "C" void kernel_launch(void* const* d_in, const int* in_sizes, int n_in,
                              void* d_out, int out_size, void* d_ws, size_t ws_size,
                              hipStream_t stream) {
    const float* h0   = (const float*)d_in[0];
    const float* h1   = (const float*)d_in[1];
    const float* r    = (const float*)d_in[2];
    const float* b00  = (const float*)d_in[3];
    const float* b01  = (const float*)d_in[4];
    const float* b10  = (const float*)d_in[5];
    const float* b11  = (const float*)d_in[6];
    const float* rw1  = (const float*)d_in[7];
    // d_in[8] = rb1: cancels inside BatchNorm
    const float* rg1  = (const float*)d_in[9];
    const float* rbe1 = (const float*)d_in[10];
    const float* rw2  = (const float*)d_in[11];
    const float* rb2  = (const float*)d_in[12];
    const float* rg2  = (const float*)d_in[13];
    const float* rbe2 = (const float*)d_in[14];
    const float* w300 = (const float*)d_in[15];
    const float* bw300= (const float*)d_in[16];
    const float* w301 = (const float*)d_in[17];
    const float* bw301= (const float*)d_in[18];
    const float* w310 = (const float*)d_in[19];
    const float* bw310= (const float*)d_in[20];
    const float* w311 = (const float*)d_in[21];
    const float* bw311= (const float*)d_in[22];
    const float* Wself0 = (const float*)d_in[23];
    const float* Wself1 = (const float*)d_in[24];
    const int* esrc = (const int*)d_in[25];
    const int* edst = (const int*)d_in[26];
    float* out = (float*)d_out;
    float* wsf = (float*)d_ws;

    static bool attr_set = false;
    if (!attr_set) {
        hipFuncSetAttribute((const void*)k_main,
                            hipFuncAttributeMaxDynamicSharedMemorySize, 114688);
        attr_set = true;
    }

    hipMemsetAsync(d_out, 0, (size_t)out_size * sizeof(float), stream);
    hipMemsetAsync(d_ws, 0, 8192 * sizeof(float), stream);   // stats + deg region

    k_prep<<<128, 256, 0, stream>>>(rw2, w300, w301, w310, w311,
                                    bw300, bw301, bw310, bw311, wsf);
    k_stats1<<<256, 256, 0, stream>>>(r, edst, wsf);
    k_stats2<<<512, 256, 0, stream>>>(r, rw1, rg1, rbe1, rb2, wsf);
    k_finalize<<<1, 128, 0, stream>>>(rw1, rg1, rbe1, rg2, rbe2, wsf);
    k_main<<<256, 512, 114688, stream>>>(r, h0, h1, b00, b01, b10, b11, rb2,
                                         esrc, edst, wsf, out);
    k_final<<<1024, 256, 0, stream>>>(h0, h1, Wself0, Wself1, wsf, out);
}

// Round 3
// 439.719 us; speedup vs baseline: 1.5826x; 1.0894x over previous
//
#include <hip/hip_runtime.h>

#define N_NODES 4096
#define N_EDGES 65536
#define MID 32
#define BN_EPS 1e-5f

// ---- workspace layout ----
// float offsets:
#define WS_RSUM    0
#define WS_RSUMSQ  1
#define WS_SUM2    16     // [4][32]
#define WS_SUMSQ2  144
#define WS_ALPHA1  272
#define WS_BETA1   400
#define WS_A2      528
#define WS_S2      656
#define WS_W2T     16384  // [4][32][32] fp32
#define WS_MSG_F   262144 // [E][64] fp32 messages (byte 1048576, 16.78 MB)
// int offsets (on (int*)wsf):
#define WS_DEG_I   1024   // int[4096]
#define WS_CUR_I   5120   // int[4096]
#define WS_OFFS_I  9216   // int[4097]
#define WS_ELIST_I 65536  // int[65536] (byte 262144)
// byte offsets:
#define WSB_W3ABC  98304  // 768 cols x 32 bf16 [col][k]: 0-255 p00, 256-511 p01, 512-767 p10
#define WSB_W311   147456 // 768 cols x 32 bf16 [col'][k], col' = f*256 + m*16 + i
#define WSB_B3     196608 // 1536 fp32

typedef short bf16x8 __attribute__((ext_vector_type(8)));
typedef float f32x4  __attribute__((ext_vector_type(4)));

__device__ __forceinline__ unsigned short f2bf(float x) {
    unsigned u = __float_as_uint(x);
    u += 0x7fffu + ((u >> 16) & 1u);   // RNE
    return (unsigned short)(u >> 16);
}

// ---------- K0: build weight images ----------
__global__ void k_prep(const float* __restrict__ rw2, const float* __restrict__ w300,
                       const float* __restrict__ w301, const float* __restrict__ w310,
                       const float* __restrict__ w311,
                       const float* __restrict__ bw300, const float* __restrict__ bw301,
                       const float* __restrict__ bw310, const float* __restrict__ bw311,
                       float* __restrict__ wsf) {
    int t = blockIdx.x * 256 + threadIdx.x;   // grid 128x256
    char* wsb = (char*)wsf;
    if (t < 4096) {   // W2T [p][c][k] <- rw2 [p][k][c]
        int p = t >> 10, rem = t & 1023, c = rem >> 5, k = rem & 31;
        wsf[WS_W2T + t] = rw2[(p << 10) + (k << 5) + c];
    }
    if (t < 24576) {  // 768 cols x 32 k
        int col = t >> 5, k = t & 31;
        float v;
        if (col < 256)      v = w300[(k << 8) + col];
        else if (col < 512) v = w301[(k << 8) + (col - 256)];
        else                v = w310[(k << 8) + (col - 512)];
        ((unsigned short*)(wsb + WSB_W3ABC))[t] = f2bf(v);
        int f = col >> 8, rem = col & 255;
        ((unsigned short*)(wsb + WSB_W311))[t] = f2bf(w311[k * 768 + rem * 3 + f]);
    }
    if (t < 1536) {   // b3 image
        float v;
        if (t < 256)      v = bw300[t];
        else if (t < 512) v = bw301[t - 256];
        else if (t < 768) v = bw310[t - 512];
        else { int idx = t - 768; int f = idx >> 8, rem = idx & 255; v = bw311[rem * 3 + f]; }
        ((float*)(wsb + WSB_B3))[t] = v;
    }
}

// ---------- K1: stats of r + degree counts ----------
__global__ void k_stats1(const float* __restrict__ r, const int* __restrict__ edst,
                         float* __restrict__ wsf) {
    int t = blockIdx.x * 256 + threadIdx.x;
    float v = r[t];
    atomicAdd(((int*)wsf) + WS_DEG_I + edst[t], 1);
    float s = v, ss = v * v;
#pragma unroll
    for (int mk = 32; mk >= 1; mk >>= 1) {
        s  += __shfl_xor(s,  mk, 64);
        ss += __shfl_xor(ss, mk, 64);
    }
    __shared__ float ls[4], lss[4];
    int lane = threadIdx.x & 63, wv = threadIdx.x >> 6;
    if (lane == 0) { ls[wv] = s; lss[wv] = ss; }
    __syncthreads();
    if (threadIdx.x == 0) {
        atomicAdd(wsf + WS_RSUM,   ls[0] + ls[1] + ls[2] + ls[3]);
        atomicAdd(wsf + WS_RSUMSQ, lss[0] + lss[1] + lss[2] + lss[3]);
    }
}

// ---------- K2: stats of layer-2 pre-activations ----------
__global__ void __launch_bounds__(256) k_stats2(const float* __restrict__ r,
        const float* __restrict__ rw1, const float* __restrict__ rg1,
        const float* __restrict__ rbe1, const float* __restrict__ rb2,
        float* __restrict__ wsf) {
    int lane = threadIdx.x & 63;
    int wv = threadIdx.x >> 6;
    int phalf = __builtin_amdgcn_readfirstlane(wv & 1);
    int e = blockIdx.x * 128 + ((wv >> 1) << 6) + lane;     // grid 512 blocks
    float rv = r[e];
    float mu_r  = wsf[WS_RSUM] * (1.f / N_EDGES);
    float var_r = wsf[WS_RSUMSQ] * (1.f / N_EDGES) - mu_r * mu_r;
    __shared__ float sacc[128], sacc2[128];
    if (threadIdx.x < 128) { sacc[threadIdx.x] = 0.f; sacc2[threadIdx.x] = 0.f; }
    __syncthreads();
    for (int pp = 0; pp < 2; ++pp) {
        int p = __builtin_amdgcn_readfirstlane(phalf * 2 + pp);
        float y1[MID];
#pragma unroll
        for (int k = 0; k < MID; ++k) {
            float w1 = rw1[p * 32 + k];
            float al = w1 * rg1[p * 32 + k] * rsqrtf(w1 * w1 * var_r + BN_EPS);
            y1[k] = fmaxf(0.f, al * (rv - mu_r) + rbe1[p * 32 + k]);
        }
        for (int c = 0; c < MID; ++c) {
            float x = rb2[p * 32 + c];
#pragma unroll
            for (int k = 0; k < MID; ++k) x += y1[k] * wsf[WS_W2T + p * 1024 + c * 32 + k];
            float xs = x, xx = x * x;
#pragma unroll
            for (int mk = 32; mk >= 1; mk >>= 1) {
                xs += __shfl_xor(xs, mk, 64);
                xx += __shfl_xor(xx, mk, 64);
            }
            if (lane == 0) { atomicAdd(&sacc[p * 32 + c], xs); atomicAdd(&sacc2[p * 32 + c], xx); }
        }
    }
    __syncthreads();
    if (threadIdx.x < 128) {
        atomicAdd(wsf + WS_SUM2   + threadIdx.x, sacc[threadIdx.x]);
        atomicAdd(wsf + WS_SUMSQ2 + threadIdx.x, sacc2[threadIdx.x]);
    }
}

// ---------- K3: finalize BN affine params ----------
__global__ void k_finalize(const float* __restrict__ rw1, const float* __restrict__ rg1,
                           const float* __restrict__ rbe1, const float* __restrict__ rg2,
                           const float* __restrict__ rbe2, float* __restrict__ wsf) {
    int t = threadIdx.x;   // 128
    float mu_r  = wsf[WS_RSUM] * (1.f / N_EDGES);
    float var_r = wsf[WS_RSUMSQ] * (1.f / N_EDGES) - mu_r * mu_r;
    float w1 = rw1[t];
    float al = w1 * rg1[t] * rsqrtf(w1 * w1 * var_r + BN_EPS);
    wsf[WS_ALPHA1 + t] = al;
    wsf[WS_BETA1  + t] = rbe1[t] - al * mu_r;
    float mu2 = wsf[WS_SUM2 + t] * (1.f / N_EDGES);
    float v2  = wsf[WS_SUMSQ2 + t] * (1.f / N_EDGES) - mu2 * mu2;
    float a2  = rg2[t] * rsqrtf(v2 + BN_EPS);
    wsf[WS_A2 + t] = a2;
    wsf[WS_S2 + t] = rbe2[t] - mu2 * a2;
}

// ---------- K3b: exclusive prefix scan of deg -> offs, cur ----------
__global__ void __launch_bounds__(1024) k_scan(float* __restrict__ wsf) {
    __shared__ int sdata[1024];
    int t = threadIdx.x;
    const int* deg = ((const int*)wsf) + WS_DEG_I;
    int* offs = ((int*)wsf) + WS_OFFS_I;
    int* cur  = ((int*)wsf) + WS_CUR_I;
    int v0 = deg[t * 4], v1 = deg[t * 4 + 1], v2 = deg[t * 4 + 2], v3 = deg[t * 4 + 3];
    sdata[t] = v0 + v1 + v2 + v3;
    __syncthreads();
    for (int off = 1; off < 1024; off <<= 1) {
        int x = sdata[t];
        int y = (t >= off) ? sdata[t - off] : 0;
        __syncthreads();
        sdata[t] = x + y;
        __syncthreads();
    }
    int excl = (t == 0) ? 0 : sdata[t - 1];
    int o0 = excl, o1 = excl + v0, o2 = o1 + v1, o3 = o2 + v2;
    offs[t * 4] = o0;     cur[t * 4] = o0;
    offs[t * 4 + 1] = o1; cur[t * 4 + 1] = o1;
    offs[t * 4 + 2] = o2; cur[t * 4 + 2] = o2;
    offs[t * 4 + 3] = o3; cur[t * 4 + 3] = o3;
    if (t == 1023) offs[4096] = sdata[1023];
}

// ---------- K3c: bucket edges by dst ----------
__global__ void k_bucket(const int* __restrict__ edst, float* __restrict__ wsf) {
    int e = blockIdx.x * 256 + threadIdx.x;
    int d = edst[e];
    int* cur   = ((int*)wsf) + WS_CUR_I;
    int* elist = ((int*)wsf) + WS_ELIST_I;
    int pos = atomicAdd(&cur[d], 1);
    elist[pos] = e;
}

// ---------- K4: MFMA message kernel (no output atomics; coalesced msg records) ----------
// block = 512 threads (8 waves), 256 edges/block, grid 256 blocks.
// LDS: w3l = 49152 B ; y2b = 65536 B ; total 114688 B
__global__ void __launch_bounds__(512, 1) k_msg(const float* __restrict__ r,
        const float* __restrict__ h0, const float* __restrict__ h1,
        const float* __restrict__ b00, const float* __restrict__ b01,
        const float* __restrict__ b10, const float* __restrict__ b11,
        const float* __restrict__ rb2,
        const int* __restrict__ esrc,
        const float* __restrict__ wsf, float* __restrict__ msg) {
    extern __shared__ char smem[];
    short* w3l = (short*)smem;
    char*  y2b = smem + 49152;
    const char* wsb = (const char*)wsf;
    int t = threadIdx.x;
    {
        const float4* src = (const float4*)(wsb + WSB_W3ABC);
        float4* dst = (float4*)w3l;
#pragma unroll
        for (int i = 0; i < 6; ++i) dst[i * 512 + t] = src[i * 512 + t];
    }
    int wv = t >> 6, lane = t & 63;
    int eb = blockIdx.x << 8;

    // ---- phase 1: y2 (fp32) -> bf16 chunks in LDS ----
    {
        int el = ((wv & 3) << 6) | lane;
        int ph = __builtin_amdgcn_readfirstlane(wv >> 2);
        float rv = r[eb + el];
#pragma unroll
        for (int pp = 0; pp < 2; ++pp) {
            int p = __builtin_amdgcn_readfirstlane(ph * 2 + pp);
            float y1[MID];
#pragma unroll
            for (int k = 0; k < MID; ++k)
                y1[k] = fmaxf(0.f, wsf[WS_ALPHA1 + p * 32 + k] * rv + wsf[WS_BETA1 + p * 32 + k]);
            unsigned short y2h[MID];
#pragma unroll
            for (int c = 0; c < MID; ++c) {
                float x = rb2[p * 32 + c];
#pragma unroll
                for (int k = 0; k < MID; ++k) x += y1[k] * wsf[WS_W2T + p * 1024 + c * 32 + k];
                float y2v = fmaxf(0.f, wsf[WS_A2 + p * 32 + c] * x + wsf[WS_S2 + p * 32 + c]);
                y2h[c] = f2bf(y2v);
            }
#pragma unroll
            for (int q = 0; q < 4; ++q) {
                int4 pk;
                pk.x = (int)y2h[q * 8 + 0] | ((int)y2h[q * 8 + 1] << 16);
                pk.y = (int)y2h[q * 8 + 2] | ((int)y2h[q * 8 + 3] << 16);
                pk.z = (int)y2h[q * 8 + 4] | ((int)y2h[q * 8 + 5] << 16);
                pk.w = (int)y2h[q * 8 + 6] | ((int)y2h[q * 8 + 7] << 16);
                *(int4*)(y2b + p * 16384 + q * 4096 + el * 16) = pk;
            }
        }
    }
    __syncthreads();

    // ---- phase 2: per-16-edge-group MFMA + apply ----
    int quad = lane >> 4, lq = lane & 15;
    const float* b3img = (const float*)(wsb + WSB_B3);
    const short* w3g11 = (const short*)(wsb + WSB_W311);

#pragma unroll 1
    for (int g2 = 0; g2 < 2; ++g2) {
        int g = wv * 2 + g2;
        int el = g * 16 + lq;
        int e = eb + el;
        int s = esrc[e];
        bf16x8 bfr[4];
#pragma unroll
        for (int p = 0; p < 4; ++p)
            bfr[p] = *(const bf16x8*)(y2b + p * 16384 + quad * 4096 + el * 16);
        float h0q[4];
#pragma unroll
        for (int rr = 0; rr < 4; ++rr) h0q[rr] = h0[s * 16 + quad * 4 + rr];
        float h1v[4][3];
#pragma unroll
        for (int rr = 0; rr < 4; ++rr)
#pragma unroll
            for (int qq = 0; qq < 3; ++qq) h1v[rr][qq] = h1[s * 48 + (quad * 4 + rr) * 3 + qq];

        float acc0[4] = {0.f, 0.f, 0.f, 0.f};
        float d01q[4] = {0.f, 0.f, 0.f, 0.f};
        float b00v = b00[e];

        // ---- pair (0,0) ----
#pragma unroll
        for (int m = 0; m < 16; ++m) {
            bf16x8 af = *(const bf16x8*)(w3l + (m * 16 + lq) * 32 + quad * 8);
            f32x4 dd = __builtin_amdgcn_mfma_f32_16x16x32_bf16(af, bfr[0], (f32x4){0.f,0.f,0.f,0.f}, 0, 0, 0);
            float4 b3v = *(const float4*)(b3img + m * 16 + quad * 4);
            float partial = (dd[0] + b3v.x) * h0q[0] + (dd[1] + b3v.y) * h0q[1]
                          + (dd[2] + b3v.z) * h0q[2] + (dd[3] + b3v.w) * h0q[3];
            partial += __shfl_xor(partial, 16);
            partial += __shfl_xor(partial, 32);
            float v = b00v * partial;
            acc0[m & 3] += (quad == (m >> 2)) ? v : 0.f;
        }
        // ---- pair (0,1) ----
#pragma unroll
        for (int m = 0; m < 16; ++m) {
            bf16x8 af = *(const bf16x8*)(w3l + (256 + m * 16 + lq) * 32 + quad * 8);
            f32x4 dd = __builtin_amdgcn_mfma_f32_16x16x32_bf16(af, bfr[1], (f32x4){0.f,0.f,0.f,0.f}, 0, 0, 0);
            float4 b3v = *(const float4*)(b3img + 256 + m * 16 + quad * 4);
            float partial = (dd[0] + b3v.x) * h0q[0] + (dd[1] + b3v.y) * h0q[1]
                          + (dd[2] + b3v.z) * h0q[2] + (dd[3] + b3v.w) * h0q[3];
            partial += __shfl_xor(partial, 16);
            partial += __shfl_xor(partial, 32);
            d01q[m & 3] += (quad == (m >> 2)) ? partial : 0.f;
        }
        // ---- pair (1,0) ----
        {
            float bq0 = b10[e * 3 + 0], bq1 = b10[e * 3 + 1], bq2 = b10[e * 3 + 2];
            float gq[4];
#pragma unroll
            for (int rr = 0; rr < 4; ++rr)
                gq[rr] = bq0 * h1v[rr][0] + bq1 * h1v[rr][1] + bq2 * h1v[rr][2];
#pragma unroll
            for (int m = 0; m < 16; ++m) {
                bf16x8 af = *(const bf16x8*)(w3l + (512 + m * 16 + lq) * 32 + quad * 8);
                f32x4 dd = __builtin_amdgcn_mfma_f32_16x16x32_bf16(af, bfr[2], (f32x4){0.f,0.f,0.f,0.f}, 0, 0, 0);
                float4 b3v = *(const float4*)(b3img + 512 + m * 16 + quad * 4);
                float partial = (dd[0] + b3v.x) * gq[0] + (dd[1] + b3v.y) * gq[1]
                              + (dd[2] + b3v.z) * gq[2] + (dd[3] + b3v.w) * gq[3];
                partial += __shfl_xor(partial, 16);
                partial += __shfl_xor(partial, 32);
                acc0[m & 3] += (quad == (m >> 2)) ? partial : 0.f;
            }
        }
        // coalesced out0 record
        {
            float4 w = {acc0[0], acc0[1], acc0[2], acc0[3]};
            *(float4*)(msg + (size_t)e * 64 + quad * 4) = w;
        }

        // ---- pair (1,1) ----
        float T[4][3][3];
        {
            float basv[3][3][3];
#pragma unroll
            for (int o = 0; o < 3; ++o)
#pragma unroll
                for (int qq = 0; qq < 3; ++qq)
#pragma unroll
                    for (int f = 0; f < 3; ++f)
                        basv[o][qq][f] = b11[e * 27 + o * 9 + qq * 3 + f];
#pragma unroll
            for (int rr = 0; rr < 4; ++rr)
#pragma unroll
                for (int o = 0; o < 3; ++o)
#pragma unroll
                    for (int f = 0; f < 3; ++f)
                        T[rr][o][f] = h1v[rr][0] * basv[o][0][f] + h1v[rr][1] * basv[o][1][f]
                                    + h1v[rr][2] * basv[o][2][f];
        }
        float m1[4][3];
#pragma unroll
        for (int rr = 0; rr < 4; ++rr)
#pragma unroll
            for (int o = 0; o < 3; ++o) m1[rr][o] = 0.f;
#pragma unroll 1
        for (int f = 0; f < 3; ++f) {
#pragma unroll
            for (int m = 0; m < 16; ++m) {
                int colb = f * 256 + m * 16 + lq;
                bf16x8 af = *(const bf16x8*)(w3g11 + colb * 32 + quad * 8);
                f32x4 dd = __builtin_amdgcn_mfma_f32_16x16x32_bf16(af, bfr[3], (f32x4){0.f,0.f,0.f,0.f}, 0, 0, 0);
                float4 b3v = *(const float4*)(b3img + 768 + f * 256 + m * 16 + quad * 4);
                float dr0 = dd[0] + b3v.x, dr1 = dd[1] + b3v.y, dr2 = dd[2] + b3v.z, dr3 = dd[3] + b3v.w;
#pragma unroll
                for (int o = 0; o < 3; ++o) {
                    float po = dr0 * T[0][o][f] + dr1 * T[1][o][f] + dr2 * T[2][o][f] + dr3 * T[3][o][f];
                    po += __shfl_xor(po, 16);
                    po += __shfl_xor(po, 32);
                    m1[m & 3][o] += (quad == (m >> 2)) ? po : 0.f;
                }
            }
        }
        float b01v0 = b01[e * 3 + 0], b01v1 = b01[e * 3 + 1], b01v2 = b01[e * 3 + 2];
#pragma unroll
        for (int rr = 0; rr < 4; ++rr) {
            m1[rr][0] += b01v0 * d01q[rr];
            m1[rr][1] += b01v1 * d01q[rr];
            m1[rr][2] += b01v2 * d01q[rr];
        }
        // coalesced out1 record: 12 floats at msg[e*64 + 16 + quad*12]
        {
            float* base = msg + (size_t)e * 64 + 16 + quad * 12;
            float4 w0 = {m1[0][0], m1[0][1], m1[0][2], m1[1][0]};
            float4 w1 = {m1[1][1], m1[1][2], m1[2][0], m1[2][1]};
            float4 w2 = {m1[2][2], m1[3][0], m1[3][1], m1[3][2]};
            *(float4*)(base)     = w0;
            *(float4*)(base + 4) = w1;
            *(float4*)(base + 8) = w2;
        }
    }
}

// ---------- K5: gather per node, /cnt, + self-interaction ----------
__global__ void __launch_bounds__(256) k_gather(const float* __restrict__ h0,
        const float* __restrict__ h1, const float* __restrict__ Wself0,
        const float* __restrict__ Wself1, const float* __restrict__ wsf,
        float* __restrict__ out) {
    int wv = threadIdx.x >> 6, lane = threadIdx.x & 63;
    int n = blockIdx.x * 4 + wv;     // grid 1024 blocks
    const int* offs  = ((const int*)wsf) + WS_OFFS_I;
    const int* elist = ((const int*)wsf) + WS_ELIST_I;
    const float* msg = wsf + WS_MSG_F;
    int start = offs[n], end = offs[n + 1];
    int deg = end - start;
    float acc = 0.f;
    for (int j0 = 0; j0 < deg; j0 += 64) {
        int cnt = min(64, deg - j0);
        int eidv = (j0 + lane < deg) ? elist[start + j0 + lane] : 0;
        for (int jj = 0; jj < cnt; ++jj) {
            int eid = __shfl(eidv, jj);
            acc += msg[(size_t)eid * 64 + lane];
        }
    }
    float self = 0.f;
    if (lane < 16) {
        int m = lane;
#pragma unroll
        for (int i = 0; i < 16; ++i) self += Wself0[m * 16 + i] * h0[n * 16 + i];
    } else {
        int idx = lane - 16; int m = idx / 3, o = idx % 3;
#pragma unroll
        for (int i = 0; i < 16; ++i) self += Wself1[m * 16 + i] * h1[n * 48 + i * 3 + o];
    }
    float c = (float)(deg > 0 ? deg : 1);
    float res = acc / c + (deg > 0 ? self : 0.f);
    if (lane < 16) out[n * 16 + lane] = res;
    else           out[65536 + n * 48 + (lane - 16)] = res;
}

extern "C" void kernel_launch(void* const* d_in, const int* in_sizes, int n_in,
                              void* d_out, int out_size, void* d_ws, size_t ws_size,
                              hipStream_t stream) {
    const float* h0   = (const float*)d_in[0];
    const float* h1   = (const float*)d_in[1];
    const float* r    = (const float*)d_in[2];
    const float* b00  = (const float*)d_in[3];
    const float* b01  = (const float*)d_in[4];
    const float* b10  = (const float*)d_in[5];
    const float* b11  = (const float*)d_in[6];
    const float* rw1  = (const float*)d_in[7];
    // d_in[8] = rb1: cancels inside BatchNorm
    const float* rg1  = (const float*)d_in[9];
    const float* rbe1 = (const float*)d_in[10];
    const float* rw2  = (const float*)d_in[11];
    const float* rb2  = (const float*)d_in[12];
    const float* rg2  = (const float*)d_in[13];
    const float* rbe2 = (const float*)d_in[14];
    const float* w300 = (const float*)d_in[15];
    const float* bw300= (const float*)d_in[16];
    const float* w301 = (const float*)d_in[17];
    const float* bw301= (const float*)d_in[18];
    const float* w310 = (const float*)d_in[19];
    const float* bw310= (const float*)d_in[20];
    const float* w311 = (const float*)d_in[21];
    const float* bw311= (const float*)d_in[22];
    const float* Wself0 = (const float*)d_in[23];
    const float* Wself1 = (const float*)d_in[24];
    const int* esrc = (const int*)d_in[25];
    const int* edst = (const int*)d_in[26];
    float* out = (float*)d_out;
    float* wsf = (float*)d_ws;

    static bool attr_set = false;
    if (!attr_set) {
        hipFuncSetAttribute((const void*)k_msg,
                            hipFuncAttributeMaxDynamicSharedMemorySize, 114688);
        attr_set = true;
    }

    // zero stats scalars + deg histogram (floats 0..5119 = 20480 bytes)
    hipMemsetAsync(d_ws, 0, 20480, stream);

    k_prep<<<128, 256, 0, stream>>>(rw2, w300, w301, w310, w311,
                                    bw300, bw301, bw310, bw311, wsf);
    k_stats1<<<256, 256, 0, stream>>>(r, edst, wsf);
    k_stats2<<<512, 256, 0, stream>>>(r, rw1, rg1, rbe1, rb2, wsf);
    k_finalize<<<1, 128, 0, stream>>>(rw1, rg1, rbe1, rg2, rbe2, wsf);
    k_scan<<<1, 1024, 0, stream>>>(wsf);
    k_bucket<<<256, 256, 0, stream>>>(edst, wsf);
    k_msg<<<256, 512, 114688, stream>>>(r, h0, h1, b00, b01, b10, b11, rb2,
                                        esrc, wsf, wsf + WS_MSG_F);
    k_gather<<<1024, 256, 0, stream>>>(h0, h1, Wself0, Wself1, wsf, out);
}